// Round 2
// baseline (267.571 us; speedup 1.0000x reference)
//
#include <hip/hip_runtime.h>
#include <math.h>

#define NPIX 4096
#define CCH  128

typedef __attribute__((ext_vector_type(8))) short  bf8;   // 8 bf16 in 4 VGPRs
typedef __attribute__((ext_vector_type(4))) float  f4;

#define MFMA(a, b, c) __builtin_amdgcn_mfma_f32_16x16x32_bf16(a, b, c, 0, 0, 0)

__device__ __forceinline__ unsigned short f2bf(float x) {
    union { float f; unsigned u; } v; v.f = x;
    unsigned r = v.u + 0x7fffu + ((v.u >> 16) & 1u);   // RNE
    return (unsigned short)(r >> 16);
}
// pack two floats to bf16x2 (lo in low short), half-ulp RNE, 3 VALU ops
__device__ __forceinline__ unsigned pk2r(float lo, float hi) {
    union { float f; unsigned u; } a, b; a.f = hi; b.f = lo;
    return __builtin_amdgcn_perm(a.u + 0x8000u, b.u + 0x8000u, 0x07060302u);
}
// truncating pack, 1 VALU op. Used ONLY for P in flash: O and l consume the
// same packed P, so the common truncation bias cancels in O/l.
__device__ __forceinline__ unsigned pk2t(float lo, float hi) {
    union { float f; unsigned u; } a, b; a.f = hi; b.f = lo;
    return __builtin_amdgcn_perm(a.u, b.u, 0x07060302u);
}

// Workspace layout (bytes), 32 MB:
//   lbuf 0..512K     fp32 2 slices [bh][n]   (flash out)
//   wqb  1M..1.094M  bf16 [384][128]  (q rows pre-scaled by 32^-.5*log2e)
//   wob  1.5M..1.53M bf16 [128][128]
//   qh   4..8M       bf16 [bh][n][32]
//   kh   8..12M      bf16 [bh][n][32]
//   vth  12..16M     bf16 [bh*32+d][n]
//   ao   16..32M     fp32 2 slices [bh*32+d][n]

// ---------------------------------------------------------------------------
// Kernel 0: convert weights to bf16 (q rows scaled). grid 256 x 256.
// ---------------------------------------------------------------------------
__global__ __launch_bounds__(256) void wconv_kernel(
    const float* __restrict__ wq, const float* __restrict__ wo,
    unsigned short* __restrict__ wqb, unsigned short* __restrict__ wob)
{
    const float qs2 = 0.17677669529663687f * 1.4426950408889634f;
    int i = blockIdx.x * 256 + threadIdx.x;       // 0..65535
    if (i < 49152) {
        float f = wq[i];
        if (i < 16384) f *= qs2;                  // q rows 0..127
        wqb[i] = f2bf(f);
    } else {
        int j = i - 49152;
        wob[j] = f2bf(wo[j]);
    }
}

// ---------------------------------------------------------------------------
// Kernel 1: fused LayerNorm + QKV MFMA GEMM. grid (1024, 2) x 256 thr.
// (R7-proven config.)
// ---------------------------------------------------------------------------
__global__ __launch_bounds__(256, 8) void lnqkv_kernel(
    const float* __restrict__ x, const float* __restrict__ g,
    const float* __restrict__ bvec, const unsigned short* __restrict__ wqb,
    unsigned short* __restrict__ qh, unsigned short* __restrict__ kh,
    unsigned short* __restrict__ vth)
{
    const int blk  = blockIdx.x;
    const int part = blockIdx.y;        // 0: o-tiles 0..11, 1: 12..23
    const int b  = blk >> 8;
    const int n0 = (blk & 255) << 4;
    const int t  = threadIdx.x;

    __shared__ float xs[CCH * 17];             // [c][pix], stride 17
    __shared__ float red0[16][16];
    __shared__ float red1[16][16];
    __shared__ float mean_s[16];
    __shared__ float rstd_s[16];
    __shared__ unsigned short xnb[16 * 138];   // bf16 [pix][c], stride 138

    const float* xb = x + (size_t)b * CCH * NPIX + n0;
#pragma unroll
    for (int k = 0; k < 8; ++k) {
        int e = k * 256 + t;
        int c = e >> 4, p = e & 15;
        xs[c * 17 + p] = xb[(size_t)c * NPIX + p];
    }
    __syncthreads();

    {
        int pix = t & 15, cg = t >> 4;
        float s = 0.f, s2 = 0.f;
#pragma unroll
        for (int cc = 0; cc < 8; ++cc) {
            float v = xs[(cg * 8 + cc) * 17 + pix];
            s += v; s2 += v * v;
        }
        red0[cg][pix] = s; red1[cg][pix] = s2;
    }
    __syncthreads();
    if (t < 16) {
        float s = 0.f, s2 = 0.f;
#pragma unroll
        for (int cg = 0; cg < 16; ++cg) { s += red0[cg][t]; s2 += red1[cg][t]; }
        float mu  = s * (1.f / 128.f);
        float var = s2 * (1.f / 128.f) - mu * mu;
        mean_s[t] = mu;
        rstd_s[t] = rsqrtf(var + 1e-5f);
    }
    __syncthreads();

    // normalize + pack into LDS: thread -> (pix = t>>4, c0 = (t&15)*8)
    {
        const int pix = t >> 4;
        const int c0  = (t & 15) * 8;
        const float mu = mean_s[pix], rs = rstd_s[pix];
#pragma unroll
        for (int i = 0; i < 4; ++i) {
            int c = c0 + 2 * i;
            float f0 = (xs[c * 17 + pix]       - mu) * rs * g[c]     + bvec[c];
            float f1 = (xs[(c + 1) * 17 + pix] - mu) * rs * g[c + 1] + bvec[c + 1];
            *(unsigned*)&xnb[pix * 138 + c] = pk2r(f0, f1);
        }
    }
    __syncthreads();

    // MFMA GEMM: wave wv covers 3 o-tiles of this part.
    const int wv   = t >> 6;
    const int l16  = t & 15;
    const int quad = (t & 63) >> 4;

    for (int it = 0; it < 3; ++it) {
        const int ot = part * 12 + wv * 3 + it;   // 0-7 q, 8-15 k, 16-23 v
        const unsigned short* wr = wqb + (size_t)(ot * 16 + l16) * CCH;
        f4 acc = {0.f, 0.f, 0.f, 0.f};
#pragma unroll
        for (int kk = 0; kk < 4; ++kk) {
            const bf8 a = *(const bf8*)&wr[kk * 32 + quad * 8];
            const unsigned short* xr = &xnb[l16 * 138 + kk * 32 + quad * 8];
            union { unsigned u[4]; bf8 v; } bx;
            bx.u[0] = *(const unsigned*)&xr[0];
            bx.u[1] = *(const unsigned*)&xr[2];
            bx.u[2] = *(const unsigned*)&xr[4];
            bx.u[3] = *(const unsigned*)&xr[6];
            acc = MFMA(a, bx.v, acc);
        }
        // C-frag: col(px)=l16, row o = ot*16 + quad*4 + r
        if (ot < 16) {
            const int h  = (ot >> 1) & 3;
            const int d0 = (ot & 1) * 16 + quad * 4;
            const int bh = b * 4 + h;
            unsigned short* dst = ((ot < 8) ? qh : kh)
                                + ((size_t)bh * NPIX + n0 + l16) * 32 + d0;
            uint2 wp;
            wp.x = pk2r(acc.x, acc.y);
            wp.y = pk2r(acc.z, acc.w);
            *(uint2*)dst = wp;
        } else {
            const int bh = b * 4 + ((ot - 16) >> 1);
            const int dv = ((ot - 16) & 1) * 16 + quad * 4;
#pragma unroll
            for (int r = 0; r < 4; ++r)
                vth[((size_t)bh * 32 + dv + r) * NPIX + n0 + l16] = f2bf(acc[r]);
        }
    }
}

// ---------------------------------------------------------------------------
// Kernel 2: MFMA flash attention. R8: 512-thread blocks, 8 waves/block,
// each wave owns a 16-row q-block (qA only) -> 8192 waves total = 8
// waves/SIMD (was 4). All 8 waves load identical K/V frags per tile (L1
// dedups -> L2 traffic unchanged). P transpose in-register via gfx950
// permlane swaps (R7): zero LDS, zero lgkmcnt.
//
// S^T C-frag dwords per src lane (quad,l16): a0x=keys{4q,4q+1}, a0y={+2,+3},
// a1x=keys{16+4q,+1}, a1y={16+4q+2,+3}, all for q-col=l16. PV B-frag needs
// dest(Q1 Q0, dword j1 j0) = src(quad = Q0 j1, reg = Q1 j0):
//   step1: {s0,s1} = pl32(a0w, a1w); step2: {d0,d1} = pl16(s0, s1).
// ---------------------------------------------------------------------------
struct Frags { bf8 k0, k1, v0, v1; };

__device__ __forceinline__ void loadFrags(Frags& f,
    const unsigned short* __restrict__ khb, const unsigned short* __restrict__ vhb,
    int j0, int l16, int quad)
{
    const size_t ka0 = (size_t)(j0 + l16) * 32 + quad * 8;
    f.k0 = *(const bf8*)&khb[ka0];
    f.k1 = *(const bf8*)&khb[ka0 + 16 * 32];
    const size_t va0 = (size_t)l16 * NPIX + j0 + quad * 8;
    f.v0 = *(const bf8*)&vhb[va0];
    f.v1 = *(const bf8*)&vhb[va0 + (size_t)16 * NPIX];
}

// in-register S^T -> PV-B-frag transpose: 2x permlane32_swap + 2x permlane16_swap
__device__ __forceinline__ void xpose(unsigned x0, unsigned y0,
                                      unsigned x1, unsigned y1,
                                      unsigned* u /*[4]*/)
{
    auto sx = __builtin_amdgcn_permlane32_swap(x0, x1, false, false);
    auto sy = __builtin_amdgcn_permlane32_swap(y0, y1, false, false);
    auto dx = __builtin_amdgcn_permlane16_swap(sx[0], sx[1], false, false);
    auto dy = __builtin_amdgcn_permlane16_swap(sy[0], sy[1], false, false);
    u[0] = dx[0]; u[1] = dy[0]; u[2] = dx[1]; u[3] = dy[1];
}

__device__ __forceinline__ void tileCompute(const Frags& f,
    const bf8 qA, const bf8 ones,
    f4& o00, f4& o10, f4& lA)
{
    const f4 z = {0.f, 0.f, 0.f, 0.f};
    f4 sA0 = MFMA(f.k0, qA, z);
    f4 sA1 = MFMA(f.k1, qA, z);

    // P = exp2(S), packed as key-pair dwords (truncating)
    const unsigned a0x = pk2t(__builtin_amdgcn_exp2f(sA0.x), __builtin_amdgcn_exp2f(sA0.y));
    const unsigned a0y = pk2t(__builtin_amdgcn_exp2f(sA0.z), __builtin_amdgcn_exp2f(sA0.w));
    const unsigned a1x = pk2t(__builtin_amdgcn_exp2f(sA1.x), __builtin_amdgcn_exp2f(sA1.y));
    const unsigned a1y = pk2t(__builtin_amdgcn_exp2f(sA1.z), __builtin_amdgcn_exp2f(sA1.w));

    union { unsigned u[4]; bf8 v; } pA;
    xpose(a0x, a0y, a1x, a1y, pA.u);

    o00 = MFMA(f.v0, pA.v, o00);
    o10 = MFMA(f.v1, pA.v, o10);
    lA  = MFMA(ones, pA.v, lA);
}

__global__ __launch_bounds__(512, 8) void flash_kernel(
    const unsigned short* __restrict__ qh, const unsigned short* __restrict__ kh,
    const unsigned short* __restrict__ vth,
    float* __restrict__ ao, float* __restrict__ lbuf)
{
    const int blk = blockIdx.x;
    const int bh  = (blk & 7) + 8 * ((blk >> 3) & 1);   // XCD-local per bh
    const int rem = blk >> 4;
    const int qt  = rem & 31;
    const int ks  = rem >> 5;                            // 0..1
    const int t   = threadIdx.x;
    const int wv  = t >> 6;                              // 0..7
    const int l16 = t & 15;
    const int quad = (t & 63) >> 4;
    const int q0  = qt * 128 + wv * 16;

    const size_t qbaseA = ((size_t)bh * NPIX + q0 + l16) * 32 + quad * 8;
    const bf8 qA = *(const bf8*)&qh[qbaseA];

    const unsigned short* khb = kh  + (size_t)bh * NPIX * 32;
    const unsigned short* vhb = vth + (size_t)bh * 32 * NPIX;

    const short one = (short)0x3f80;
    const bf8 ones = {one, one, one, one, one, one, one, one};

    const f4 z = {0.f, 0.f, 0.f, 0.f};
    f4 o00 = z, o10 = z, lA = z;

    const int jbase = ks * 2048;
    Frags fa, fb;
    loadFrags(fa, khb, vhb, jbase, l16, quad);
    for (int jt = 0; jt < 64; jt += 2) {
        loadFrags(fb, khb, vhb, jbase + (jt + 1) * 32, l16, quad);
        tileCompute(fa, qA, ones, o00, o10, lA);
        loadFrags(fa, khb, vhb, jbase + (jt + 2) * 32, l16, quad);  // tail over-read stays in ws
        tileCompute(fb, qA, ones, o00, o10, lA);
    }

    // epilogue: fp32 stores; waves 0..7 cover 128 contiguous cols per row
    float* aos = ao + (size_t)ks * 2097152;
    float* lbs = lbuf + (size_t)ks * 65536;
    float* aoA = aos + (size_t)bh * 32 * NPIX + q0 + l16;
#pragma unroll
    for (int r = 0; r < 4; ++r) {
        aoA[(size_t)(quad * 4 + r) * NPIX]      = o00[r];
        aoA[(size_t)(16 + quad * 4 + r) * NPIX] = o10[r];
    }
    if (quad == 0) {
        lbs[(size_t)bh * NPIX + q0 + l16] = lA.x;
    }
}

// ---------------------------------------------------------------------------
// Kernel 3: sum 2 fp32 O-slices (float4), normalize, MFMA projection + bias.
// grid (512, 2). (R7-proven config.)
// ---------------------------------------------------------------------------
__global__ __launch_bounds__(256) void proj_kernel(
    const float* __restrict__ ao, const float* __restrict__ lbuf,
    const unsigned short* __restrict__ wob, const float* __restrict__ b_out,
    float* __restrict__ out)
{
    const int blk  = blockIdx.x;
    const int part = blockIdx.y;
    const int b  = blk >> 7;
    const int n0 = (blk & 127) << 5;
    const int t  = threadIdx.x;
    const int wv = t >> 6;
    const int l16 = t & 15;
    const int quad = (t & 63) >> 4;

    __shared__ unsigned short xsb[32 * 138];   // [pix][c], stride 138
    __shared__ float linv[4][32];

    if (t < 128) {
        int h = t >> 5, p = t & 31;
        size_t li = (size_t)(b * 4 + h) * NPIX + n0 + p;
        linv[h][p] = 1.0f / (lbuf[li] + lbuf[li + 65536]);
    }
    __syncthreads();

    const float* a0 = ao + (size_t)(b * CCH) * NPIX + n0;
    const float* a1 = a0 + 2097152;
#pragma unroll
    for (int k = 0; k < 4; ++k) {
        int idx = k * 256 + t;                 // 1024 float4 slots
        int c = idx >> 3, p4 = (idx & 7) * 4;
        const float4 va = *(const float4*)&a0[(size_t)c * NPIX + p4];
        const float4 vb = *(const float4*)&a1[(size_t)c * NPIX + p4];
        const int hh = c >> 5;
        xsb[(p4 + 0) * 138 + c] = f2bf((va.x + vb.x) * linv[hh][p4 + 0]);
        xsb[(p4 + 1) * 138 + c] = f2bf((va.y + vb.y) * linv[hh][p4 + 1]);
        xsb[(p4 + 2) * 138 + c] = f2bf((va.z + vb.z) * linv[hh][p4 + 2]);
        xsb[(p4 + 3) * 138 + c] = f2bf((va.w + vb.w) * linv[hh][p4 + 3]);
    }
    __syncthreads();

    // A-frags: wob rows (o = o0 + l16), bf16 direct
    const int o0 = part * 64 + wv * 16;
    const unsigned short* wrow = wob + (size_t)(o0 + l16) * CCH;
    bf8 aw[4];
#pragma unroll
    for (int kk = 0; kk < 4; ++kk)
        aw[kk] = *(const bf8*)&wrow[kk * 32 + quad * 8];

    const f4 z = {0.f, 0.f, 0.f, 0.f};
    f4 acc[2] = {z, z};
#pragma unroll
    for (int s = 0; s < 2; ++s) {
#pragma unroll
        for (int kk = 0; kk < 4; ++kk) {
            const unsigned short* row = &xsb[(s * 16 + l16) * 138 + kk * 32 + quad * 8];
            union { unsigned u[4]; bf8 v; } pb;
            pb.u[0] = *(const unsigned*)&row[0];
            pb.u[1] = *(const unsigned*)&row[2];
            pb.u[2] = *(const unsigned*)&row[4];
            pb.u[3] = *(const unsigned*)&row[6];
            acc[s] = MFMA(aw[kk], pb.v, acc[s]);
        }
    }

#pragma unroll
    for (int r = 0; r < 4; ++r) {
        const int o = o0 + quad * 4 + r;
        const float bo = b_out[o];
        float* orow = out + (size_t)(b * CCH + o) * NPIX + n0 + l16;
#pragma unroll
        for (int s = 0; s < 2; ++s)
            orow[s * 16] = acc[s][r] + bo;
    }
}

// ---------------------------------------------------------------------------
extern "C" void kernel_launch(void* const* d_in, const int* in_sizes, int n_in,
                              void* d_out, int out_size, void* d_ws, size_t ws_size,
                              hipStream_t stream) {
    const float* x     = (const float*)d_in[0];
    const float* g     = (const float*)d_in[1];
    const float* bvec  = (const float*)d_in[2];
    const float* w_qkv = (const float*)d_in[3];
    const float* w_out = (const float*)d_in[4];
    const float* b_out = (const float*)d_in[5];
    float* out = (float*)d_out;

    char* ws = (char*)d_ws;
    float*          lbuf = (float*)(ws);                      // 0..512K
    unsigned short* wqb  = (unsigned short*)(ws + (1u << 20));
    unsigned short* wob  = (unsigned short*)(ws + (3u << 19)); // 1.5M
    unsigned short* qh   = (unsigned short*)(ws + (4u  << 20));
    unsigned short* kh   = (unsigned short*)(ws + (8u  << 20));
    unsigned short* vth  = (unsigned short*)(ws + (12u << 20));
    float*          ao   = (float*)(ws + (16u << 20));        // 2 slices x 8MB

    wconv_kernel<<<dim3(256),     dim3(256), 0, stream>>>(w_qkv, w_out, wqb, wob);
    lnqkv_kernel<<<dim3(1024, 2), dim3(256), 0, stream>>>(x, g, bvec, wqb, qh, kh, vth);
    flash_kernel<<<dim3(1024),    dim3(512), 0, stream>>>(qh, kh, vth, ao, lbuf);
    proj_kernel <<<dim3(512, 2),  dim3(256), 0, stream>>>(ao, lbuf, wob, b_out, out);
}

// Round 3
// 144.376 us; speedup vs baseline: 1.8533x; 1.8533x over previous
//
#include <hip/hip_runtime.h>
#include <math.h>

#define NPIX 4096
#define CCH  128

typedef __attribute__((ext_vector_type(8))) short  bf8;   // 8 bf16 in 4 VGPRs
typedef __attribute__((ext_vector_type(4))) float  f4;

typedef __attribute__((address_space(1))) const unsigned gu32;
typedef __attribute__((address_space(3))) unsigned       lu32;

#define MFMA(a, b, c) __builtin_amdgcn_mfma_f32_16x16x32_bf16(a, b, c, 0, 0, 0)

__device__ __forceinline__ unsigned short f2bf(float x) {
    union { float f; unsigned u; } v; v.f = x;
    unsigned r = v.u + 0x7fffu + ((v.u >> 16) & 1u);   // RNE
    return (unsigned short)(r >> 16);
}
// pack two floats to bf16x2 (lo in low short), half-ulp RNE, 3 VALU ops
__device__ __forceinline__ unsigned pk2r(float lo, float hi) {
    union { float f; unsigned u; } a, b; a.f = hi; b.f = lo;
    return __builtin_amdgcn_perm(a.u + 0x8000u, b.u + 0x8000u, 0x07060302u);
}
// truncating pack, 1 VALU op. Used ONLY for P in flash: O and l consume the
// same packed P, so the common truncation bias cancels in O/l.
__device__ __forceinline__ unsigned pk2t(float lo, float hi) {
    union { float f; unsigned u; } a, b; a.f = hi; b.f = lo;
    return __builtin_amdgcn_perm(a.u, b.u, 0x07060302u);
}

// Workspace layout (bytes), 32 MB:
//   lbuf 0..512K     fp32 2 slices [bh][n]   (flash out)
//   wqb  1M..1.094M  bf16 [384][128]  (q rows pre-scaled by 32^-.5*log2e)
//   wob  1.5M..1.53M bf16 [128][128]
//   qh   4..8M       bf16 [bh][n][32]
//   kh   8..12M      bf16 [bh][n][32]
//   vth  12..16M     bf16 [bh*32+d][n]
//   ao   16..32M     fp32 2 slices [bh*32+d][n]

// ---------------------------------------------------------------------------
// Kernel 0: convert weights to bf16 (q rows scaled). grid 256 x 256.
// ---------------------------------------------------------------------------
__global__ __launch_bounds__(256) void wconv_kernel(
    const float* __restrict__ wq, const float* __restrict__ wo,
    unsigned short* __restrict__ wqb, unsigned short* __restrict__ wob)
{
    const float qs2 = 0.17677669529663687f * 1.4426950408889634f;
    int i = blockIdx.x * 256 + threadIdx.x;       // 0..65535
    if (i < 49152) {
        float f = wq[i];
        if (i < 16384) f *= qs2;                  // q rows 0..127
        wqb[i] = f2bf(f);
    } else {
        int j = i - 49152;
        wob[j] = f2bf(wo[j]);
    }
}

// ---------------------------------------------------------------------------
// Kernel 1: fused LayerNorm + QKV MFMA GEMM. grid (1024, 2) x 256 thr.
// (R7-proven config.)
// ---------------------------------------------------------------------------
__global__ __launch_bounds__(256, 8) void lnqkv_kernel(
    const float* __restrict__ x, const float* __restrict__ g,
    const float* __restrict__ bvec, const unsigned short* __restrict__ wqb,
    unsigned short* __restrict__ qh, unsigned short* __restrict__ kh,
    unsigned short* __restrict__ vth)
{
    const int blk  = blockIdx.x;
    const int part = blockIdx.y;        // 0: o-tiles 0..11, 1: 12..23
    const int b  = blk >> 8;
    const int n0 = (blk & 255) << 4;
    const int t  = threadIdx.x;

    __shared__ float xs[CCH * 17];             // [c][pix], stride 17
    __shared__ float red0[16][16];
    __shared__ float red1[16][16];
    __shared__ float mean_s[16];
    __shared__ float rstd_s[16];
    __shared__ unsigned short xnb[16 * 138];   // bf16 [pix][c], stride 138

    const float* xb = x + (size_t)b * CCH * NPIX + n0;
#pragma unroll
    for (int k = 0; k < 8; ++k) {
        int e = k * 256 + t;
        int c = e >> 4, p = e & 15;
        xs[c * 17 + p] = xb[(size_t)c * NPIX + p];
    }
    __syncthreads();

    {
        int pix = t & 15, cg = t >> 4;
        float s = 0.f, s2 = 0.f;
#pragma unroll
        for (int cc = 0; cc < 8; ++cc) {
            float v = xs[(cg * 8 + cc) * 17 + pix];
            s += v; s2 += v * v;
        }
        red0[cg][pix] = s; red1[cg][pix] = s2;
    }
    __syncthreads();
    if (t < 16) {
        float s = 0.f, s2 = 0.f;
#pragma unroll
        for (int cg = 0; cg < 16; ++cg) { s += red0[cg][t]; s2 += red1[cg][t]; }
        float mu  = s * (1.f / 128.f);
        float var = s2 * (1.f / 128.f) - mu * mu;
        mean_s[t] = mu;
        rstd_s[t] = rsqrtf(var + 1e-5f);
    }
    __syncthreads();

    // normalize + pack into LDS: thread -> (pix = t>>4, c0 = (t&15)*8)
    {
        const int pix = t >> 4;
        const int c0  = (t & 15) * 8;
        const float mu = mean_s[pix], rs = rstd_s[pix];
#pragma unroll
        for (int i = 0; i < 4; ++i) {
            int c = c0 + 2 * i;
            float f0 = (xs[c * 17 + pix]       - mu) * rs * g[c]     + bvec[c];
            float f1 = (xs[(c + 1) * 17 + pix] - mu) * rs * g[c + 1] + bvec[c + 1];
            *(unsigned*)&xnb[pix * 138 + c] = pk2r(f0, f1);
        }
    }
    __syncthreads();

    // MFMA GEMM: wave wv covers 3 o-tiles of this part.
    const int wv   = t >> 6;
    const int l16  = t & 15;
    const int quad = (t & 63) >> 4;

    for (int it = 0; it < 3; ++it) {
        const int ot = part * 12 + wv * 3 + it;   // 0-7 q, 8-15 k, 16-23 v
        const unsigned short* wr = wqb + (size_t)(ot * 16 + l16) * CCH;
        f4 acc = {0.f, 0.f, 0.f, 0.f};
#pragma unroll
        for (int kk = 0; kk < 4; ++kk) {
            const bf8 a = *(const bf8*)&wr[kk * 32 + quad * 8];
            const unsigned short* xr = &xnb[l16 * 138 + kk * 32 + quad * 8];
            union { unsigned u[4]; bf8 v; } bx;
            bx.u[0] = *(const unsigned*)&xr[0];
            bx.u[1] = *(const unsigned*)&xr[2];
            bx.u[2] = *(const unsigned*)&xr[4];
            bx.u[3] = *(const unsigned*)&xr[6];
            acc = MFMA(a, bx.v, acc);
        }
        // C-frag: col(px)=l16, row o = ot*16 + quad*4 + r
        if (ot < 16) {
            const int h  = (ot >> 1) & 3;
            const int d0 = (ot & 1) * 16 + quad * 4;
            const int bh = b * 4 + h;
            unsigned short* dst = ((ot < 8) ? qh : kh)
                                + ((size_t)bh * NPIX + n0 + l16) * 32 + d0;
            uint2 wp;
            wp.x = pk2r(acc.x, acc.y);
            wp.y = pk2r(acc.z, acc.w);
            *(uint2*)dst = wp;
        } else {
            const int bh = b * 4 + ((ot - 16) >> 1);
            const int dv = ((ot - 16) & 1) * 16 + quad * 4;
#pragma unroll
            for (int r = 0; r < 4; ++r)
                vth[((size_t)bh * 32 + dv + r) * NPIX + n0 + l16] = f2bf(acc[r]);
        }
    }
}

// ---------------------------------------------------------------------------
// Kernel 2: MFMA flash attention. R9: back to R1 shape (256 thr, 4 waves,
// qA+qB per wave) + per-BLOCK K/V staging in LDS via global_load_lds
// (double-buffered, 1 instr/wave/tile) — VMEM instrs /4, L2 traffic /4.
// LDS tile is XOR-swizzled (rule #21: linear LDS dest, inverse-swizzled
// global source, same swizzle on ds_read): slot = col ^ ((row>>1)&3)
// -> 2 lanes/bank per 16-lane phase on ds_read_b128 (conflict-free).
// P transpose in-register via permlane swaps (R7): see xpose().
// ---------------------------------------------------------------------------
struct Frags { bf8 k0, k1, v0, v1; };

// in-register S^T -> PV-B-frag transpose: 2x permlane32_swap + 2x permlane16_swap
__device__ __forceinline__ void xpose(unsigned x0, unsigned y0,
                                      unsigned x1, unsigned y1,
                                      unsigned* u /*[4]*/)
{
    auto sx = __builtin_amdgcn_permlane32_swap(x0, x1, false, false);
    auto sy = __builtin_amdgcn_permlane32_swap(y0, y1, false, false);
    auto dx = __builtin_amdgcn_permlane16_swap(sx[0], sx[1], false, false);
    auto dy = __builtin_amdgcn_permlane16_swap(sy[0], sy[1], false, false);
    u[0] = dx[0]; u[1] = dy[0]; u[2] = dx[1]; u[3] = dy[1];
}

__device__ __forceinline__ void tileCompute(const Frags& f,
    const bf8 qA, const bf8 qB, const bf8 ones,
    f4& o00, f4& o10, f4& o01, f4& o11, f4& lA, f4& lB)
{
    const f4 z = {0.f, 0.f, 0.f, 0.f};
    f4 sA0 = MFMA(f.k0, qA, z);
    f4 sA1 = MFMA(f.k1, qA, z);
    f4 sB0 = MFMA(f.k0, qB, z);
    f4 sB1 = MFMA(f.k1, qB, z);

    // P = exp2(S), packed as key-pair dwords (truncating)
    const unsigned a0x = pk2t(__builtin_amdgcn_exp2f(sA0.x), __builtin_amdgcn_exp2f(sA0.y));
    const unsigned a0y = pk2t(__builtin_amdgcn_exp2f(sA0.z), __builtin_amdgcn_exp2f(sA0.w));
    const unsigned a1x = pk2t(__builtin_amdgcn_exp2f(sA1.x), __builtin_amdgcn_exp2f(sA1.y));
    const unsigned a1y = pk2t(__builtin_amdgcn_exp2f(sA1.z), __builtin_amdgcn_exp2f(sA1.w));
    const unsigned b0x = pk2t(__builtin_amdgcn_exp2f(sB0.x), __builtin_amdgcn_exp2f(sB0.y));
    const unsigned b0y = pk2t(__builtin_amdgcn_exp2f(sB0.z), __builtin_amdgcn_exp2f(sB0.w));
    const unsigned b1x = pk2t(__builtin_amdgcn_exp2f(sB1.x), __builtin_amdgcn_exp2f(sB1.y));
    const unsigned b1y = pk2t(__builtin_amdgcn_exp2f(sB1.z), __builtin_amdgcn_exp2f(sB1.w));

    union { unsigned u[4]; bf8 v; } pA, pB;
    xpose(a0x, a0y, a1x, a1y, pA.u);
    xpose(b0x, b0y, b1x, b1y, pB.u);

    o00 = MFMA(f.v0, pA.v, o00); o10 = MFMA(f.v1, pA.v, o10);
    o01 = MFMA(f.v0, pB.v, o01); o11 = MFMA(f.v1, pB.v, o11);
    lA  = MFMA(ones, pA.v, lA);  lB  = MFMA(ones, pB.v, lB);
}

__global__ __launch_bounds__(256, 4) void flash_kernel(
    const unsigned short* __restrict__ qh, const unsigned short* __restrict__ kh,
    const unsigned short* __restrict__ vth,
    float* __restrict__ ao, float* __restrict__ lbuf)
{
    const int blk = blockIdx.x;
    const int bh  = (blk & 7) + 8 * ((blk >> 3) & 1);   // XCD-local per bh
    const int rem = blk >> 4;
    const int qt  = rem & 31;
    const int ks  = rem >> 5;                            // 0..1
    const int t   = threadIdx.x;
    const int wv  = t >> 6;
    const int l16 = t & 15;
    const int quad = (t & 63) >> 4;
    const int q0  = qt * 128 + wv * 32;

    // double-buffered K/V tile: [buf][K 32x(32d) | V 32dx(32n)], bf16
    __shared__ __align__(16) unsigned short kv[2][2048];

    const size_t qbaseA = ((size_t)bh * NPIX + q0 + l16) * 32 + quad * 8;
    const bf8 qA = *(const bf8*)&qh[qbaseA];
    const bf8 qB = *(const bf8*)&qh[qbaseA + 16 * 32];

    const unsigned short* khb = kh  + (size_t)bh * NPIX * 32;
    const unsigned short* vhb = vth + (size_t)bh * 32 * NPIX;

    // staging geometry: wave wv stages chunk wv (1KB): lane -> 16B slot.
    // chunk rows are multiples of 16, so swizzled col = (lane&3)^((lane>>3)&3).
    const int lane = t & 63;
    const int srow = lane >> 2;
    const int scol = (lane & 3) ^ ((lane >> 3) & 3);
    lu32* ldsbase[2];
    ldsbase[0] = (lu32*)&kv[0][wv * 512];
    ldsbase[1] = (lu32*)&kv[1][wv * 512];

    const short one = (short)0x3f80;
    const bf8 ones = {one, one, one, one, one, one, one, one};

    const f4 z = {0.f, 0.f, 0.f, 0.f};
    f4 o00 = z, o10 = z, o01 = z, o11 = z, lA = z, lB = z;

    const int jbase = ks * 2048;

    // K chunks (wv 0,1): rows = keys, source row j0+wv*16+srow, 64B rows.
    // V chunks (wv 2,3): rows = d, source row (wv-2)*16+srow, stride NPIX.
#define STAGE(bufi, j0s)                                                        \
    {                                                                           \
        const unsigned short* gsrc = (wv < 2)                                   \
            ? khb + (size_t)((j0s) + wv * 16 + srow) * 32 + scol * 8            \
            : vhb + (size_t)((wv - 2) * 16 + srow) * NPIX + (j0s) + scol * 8;   \
        __builtin_amdgcn_global_load_lds((gu32*)gsrc, ldsbase[bufi], 16, 0, 0); \
    }

    STAGE(0, jbase);
    __syncthreads();

    const int sk = (quad ^ ((l16 >> 1) & 3)) * 8;   // swizzled 16B slot (shorts)
    for (int jt = 0; jt < 64; ++jt) {
        const int cur = jt & 1;
        if (jt < 63) STAGE(cur ^ 1, jbase + (jt + 1) * 32);
        const unsigned short* kb = kv[cur];
        Frags f;
        f.k0 = *(const bf8*)&kb[l16 * 32 + sk];
        f.k1 = *(const bf8*)&kb[(16 + l16) * 32 + sk];
        f.v0 = *(const bf8*)&kb[1024 + l16 * 32 + sk];
        f.v1 = *(const bf8*)&kb[1024 + (16 + l16) * 32 + sk];
        tileCompute(f, qA, qB, ones, o00, o10, o01, o11, lA, lB);
        __syncthreads();   // drains vmcnt (stage done) + lgkm (reads done)
    }
#undef STAGE

    // epilogue: fp32 stores, full 128B line coverage per wave (A+B adjacent)
    float* aos = ao + (size_t)ks * 2097152;
    float* lbs = lbuf + (size_t)ks * 65536;
    float* aoA = aos + (size_t)bh * 32 * NPIX + q0 + l16;
    float* aoB = aoA + 16;
#pragma unroll
    for (int r = 0; r < 4; ++r) {
        aoA[(size_t)(quad * 4 + r) * NPIX]      = o00[r];
        aoA[(size_t)(16 + quad * 4 + r) * NPIX] = o10[r];
        aoB[(size_t)(quad * 4 + r) * NPIX]      = o01[r];
        aoB[(size_t)(16 + quad * 4 + r) * NPIX] = o11[r];
    }
    if (quad == 0) {
        lbs[(size_t)bh * NPIX + q0 + l16]      = lA.x;
        lbs[(size_t)bh * NPIX + q0 + 16 + l16] = lB.x;
    }
}

// ---------------------------------------------------------------------------
// Kernel 3: sum 2 fp32 O-slices (float4), normalize, MFMA projection + bias.
// grid (512, 2). (R7-proven config.)
// ---------------------------------------------------------------------------
__global__ __launch_bounds__(256) void proj_kernel(
    const float* __restrict__ ao, const float* __restrict__ lbuf,
    const unsigned short* __restrict__ wob, const float* __restrict__ b_out,
    float* __restrict__ out)
{
    const int blk  = blockIdx.x;
    const int part = blockIdx.y;
    const int b  = blk >> 7;
    const int n0 = (blk & 127) << 5;
    const int t  = threadIdx.x;
    const int wv = t >> 6;
    const int l16 = t & 15;
    const int quad = (t & 63) >> 4;

    __shared__ unsigned short xsb[32 * 138];   // [pix][c], stride 138
    __shared__ float linv[4][32];

    if (t < 128) {
        int h = t >> 5, p = t & 31;
        size_t li = (size_t)(b * 4 + h) * NPIX + n0 + p;
        linv[h][p] = 1.0f / (lbuf[li] + lbuf[li + 65536]);
    }
    __syncthreads();

    const float* a0 = ao + (size_t)(b * CCH) * NPIX + n0;
    const float* a1 = a0 + 2097152;
#pragma unroll
    for (int k = 0; k < 4; ++k) {
        int idx = k * 256 + t;                 // 1024 float4 slots
        int c = idx >> 3, p4 = (idx & 7) * 4;
        const float4 va = *(const float4*)&a0[(size_t)c * NPIX + p4];
        const float4 vb = *(const float4*)&a1[(size_t)c * NPIX + p4];
        const int hh = c >> 5;
        xsb[(p4 + 0) * 138 + c] = f2bf((va.x + vb.x) * linv[hh][p4 + 0]);
        xsb[(p4 + 1) * 138 + c] = f2bf((va.y + vb.y) * linv[hh][p4 + 1]);
        xsb[(p4 + 2) * 138 + c] = f2bf((va.z + vb.z) * linv[hh][p4 + 2]);
        xsb[(p4 + 3) * 138 + c] = f2bf((va.w + vb.w) * linv[hh][p4 + 3]);
    }
    __syncthreads();

    // A-frags: wob rows (o = o0 + l16), bf16 direct
    const int o0 = part * 64 + wv * 16;
    const unsigned short* wrow = wob + (size_t)(o0 + l16) * CCH;
    bf8 aw[4];
#pragma unroll
    for (int kk = 0; kk < 4; ++kk)
        aw[kk] = *(const bf8*)&wrow[kk * 32 + quad * 8];

    const f4 z = {0.f, 0.f, 0.f, 0.f};
    f4 acc[2] = {z, z};
#pragma unroll
    for (int s = 0; s < 2; ++s) {
#pragma unroll
        for (int kk = 0; kk < 4; ++kk) {
            const unsigned short* row = &xsb[(s * 16 + l16) * 138 + kk * 32 + quad * 8];
            union { unsigned u[4]; bf8 v; } pb;
            pb.u[0] = *(const unsigned*)&row[0];
            pb.u[1] = *(const unsigned*)&row[2];
            pb.u[2] = *(const unsigned*)&row[4];
            pb.u[3] = *(const unsigned*)&row[6];
            acc[s] = MFMA(aw[kk], pb.v, acc[s]);
        }
    }

#pragma unroll
    for (int r = 0; r < 4; ++r) {
        const int o = o0 + quad * 4 + r;
        const float bo = b_out[o];
        float* orow = out + (size_t)(b * CCH + o) * NPIX + n0 + l16;
#pragma unroll
        for (int s = 0; s < 2; ++s)
            orow[s * 16] = acc[s][r] + bo;
    }
}

// ---------------------------------------------------------------------------
extern "C" void kernel_launch(void* const* d_in, const int* in_sizes, int n_in,
                              void* d_out, int out_size, void* d_ws, size_t ws_size,
                              hipStream_t stream) {
    const float* x     = (const float*)d_in[0];
    const float* g     = (const float*)d_in[1];
    const float* bvec  = (const float*)d_in[2];
    const float* w_qkv = (const float*)d_in[3];
    const float* w_out = (const float*)d_in[4];
    const float* b_out = (const float*)d_in[5];
    float* out = (float*)d_out;

    char* ws = (char*)d_ws;
    float*          lbuf = (float*)(ws);                      // 0..512K
    unsigned short* wqb  = (unsigned short*)(ws + (1u << 20));
    unsigned short* wob  = (unsigned short*)(ws + (3u << 19)); // 1.5M
    unsigned short* qh   = (unsigned short*)(ws + (4u  << 20));
    unsigned short* kh   = (unsigned short*)(ws + (8u  << 20));
    unsigned short* vth  = (unsigned short*)(ws + (12u << 20));
    float*          ao   = (float*)(ws + (16u << 20));        // 2 slices x 8MB

    wconv_kernel<<<dim3(256),     dim3(256), 0, stream>>>(w_qkv, w_out, wqb, wob);
    lnqkv_kernel<<<dim3(1024, 2), dim3(256), 0, stream>>>(x, g, bvec, wqb, qh, kh, vth);
    flash_kernel<<<dim3(1024),    dim3(256), 0, stream>>>(qh, kh, vth, ao, lbuf);
    proj_kernel <<<dim3(512, 2),  dim3(256), 0, stream>>>(ao, lbuf, wob, b_out, out);
}

// Round 5
// 143.595 us; speedup vs baseline: 1.8634x; 1.0054x over previous
//
#include <hip/hip_runtime.h>
#include <math.h>

#define NPIX 4096
#define CCH  128

typedef __attribute__((ext_vector_type(8))) short  bf8;   // 8 bf16 in 4 VGPRs
typedef __attribute__((ext_vector_type(4))) float  f4;

typedef __attribute__((address_space(1))) const unsigned gu32;
typedef __attribute__((address_space(3))) unsigned       lu32;

#define MFMA(a, b, c) __builtin_amdgcn_mfma_f32_16x16x32_bf16(a, b, c, 0, 0, 0)

__device__ __forceinline__ unsigned short f2bf(float x) {
    union { float f; unsigned u; } v; v.f = x;
    unsigned r = v.u + 0x7fffu + ((v.u >> 16) & 1u);   // RNE
    return (unsigned short)(r >> 16);
}
// pack two floats to bf16x2 (lo in low short), half-ulp RNE, 3 VALU ops
__device__ __forceinline__ unsigned pk2r(float lo, float hi) {
    union { float f; unsigned u; } a, b; a.f = hi; b.f = lo;
    return __builtin_amdgcn_perm(a.u + 0x8000u, b.u + 0x8000u, 0x07060302u);
}
// truncating pack, 1 VALU op. Used ONLY for P in flash: O and l consume the
// same packed P, so the common truncation bias cancels in O/l.
__device__ __forceinline__ unsigned pk2t(float lo, float hi) {
    union { float f; unsigned u; } a, b; a.f = hi; b.f = lo;
    return __builtin_amdgcn_perm(a.u, b.u, 0x07060302u);
}

// Workspace layout (bytes), 32 MB:
//   lbuf 0..512K     fp32 2 slices [bh][n]   (flash out)
//   wqb  1M..1.094M  bf16 [384][128]  (q rows pre-scaled by 32^-.5*log2e)
//   wob  1.5M..1.53M bf16 [128][128]
//   qh   4..8M       bf16 [bh][n][32]
//   kh   8..12M      bf16 [bh][n][32]
//   vth  12..16M     bf16 [bh*32+d][n]
//   ao   16..32M     fp32 2 slices [bh*32+d][n]

// ---------------------------------------------------------------------------
// Kernel 0: convert weights to bf16 (q rows scaled). grid 256 x 256.
// ---------------------------------------------------------------------------
__global__ __launch_bounds__(256) void wconv_kernel(
    const float* __restrict__ wq, const float* __restrict__ wo,
    unsigned short* __restrict__ wqb, unsigned short* __restrict__ wob)
{
    const float qs2 = 0.17677669529663687f * 1.4426950408889634f;
    int i = blockIdx.x * 256 + threadIdx.x;       // 0..65535
    if (i < 49152) {
        float f = wq[i];
        if (i < 16384) f *= qs2;                  // q rows 0..127
        wqb[i] = f2bf(f);
    } else {
        int j = i - 49152;
        wob[j] = f2bf(wo[j]);
    }
}

// ---------------------------------------------------------------------------
// Kernel 1: fused LayerNorm + QKV MFMA GEMM. R10: parts MERGED — grid 1024,
// each wave covers 6 o-tiles (was 3 with the preamble duplicated across
// blockIdx.y=2). Preamble (x loads, LN reduce, bf16 pack) now runs once
// per x-tile instead of twice.
// ---------------------------------------------------------------------------
__global__ __launch_bounds__(256, 8) void lnqkv_kernel(
    const float* __restrict__ x, const float* __restrict__ g,
    const float* __restrict__ bvec, const unsigned short* __restrict__ wqb,
    unsigned short* __restrict__ qh, unsigned short* __restrict__ kh,
    unsigned short* __restrict__ vth)
{
    const int blk  = blockIdx.x;
    const int b  = blk >> 8;
    const int n0 = (blk & 255) << 4;
    const int t  = threadIdx.x;

    __shared__ float xs[CCH * 17];             // [c][pix], stride 17
    __shared__ float red0[16][16];
    __shared__ float red1[16][16];
    __shared__ float mean_s[16];
    __shared__ float rstd_s[16];
    __shared__ unsigned short xnb[16 * 138];   // bf16 [pix][c], stride 138

    const float* xb = x + (size_t)b * CCH * NPIX + n0;
#pragma unroll
    for (int k = 0; k < 8; ++k) {
        int e = k * 256 + t;
        int c = e >> 4, p = e & 15;
        xs[c * 17 + p] = xb[(size_t)c * NPIX + p];
    }
    __syncthreads();

    {
        int pix = t & 15, cg = t >> 4;
        float s = 0.f, s2 = 0.f;
#pragma unroll
        for (int cc = 0; cc < 8; ++cc) {
            float v = xs[(cg * 8 + cc) * 17 + pix];
            s += v; s2 += v * v;
        }
        red0[cg][pix] = s; red1[cg][pix] = s2;
    }
    __syncthreads();
    if (t < 16) {
        float s = 0.f, s2 = 0.f;
#pragma unroll
        for (int cg = 0; cg < 16; ++cg) { s += red0[cg][t]; s2 += red1[cg][t]; }
        float mu  = s * (1.f / 128.f);
        float var = s2 * (1.f / 128.f) - mu * mu;
        mean_s[t] = mu;
        rstd_s[t] = rsqrtf(var + 1e-5f);
    }
    __syncthreads();

    // normalize + pack into LDS: thread -> (pix = t>>4, c0 = (t&15)*8)
    {
        const int pix = t >> 4;
        const int c0  = (t & 15) * 8;
        const float mu = mean_s[pix], rs = rstd_s[pix];
#pragma unroll
        for (int i = 0; i < 4; ++i) {
            int c = c0 + 2 * i;
            float f0 = (xs[c * 17 + pix]       - mu) * rs * g[c]     + bvec[c];
            float f1 = (xs[(c + 1) * 17 + pix] - mu) * rs * g[c + 1] + bvec[c + 1];
            *(unsigned*)&xnb[pix * 138 + c] = pk2r(f0, f1);
        }
    }
    __syncthreads();

    // MFMA GEMM: wave wv covers 6 consecutive o-tiles.
    const int wv   = t >> 6;
    const int l16  = t & 15;
    const int quad = (t & 63) >> 4;

    for (int it = 0; it < 6; ++it) {
        const int ot = wv * 6 + it;               // 0-7 q, 8-15 k, 16-23 v
        const unsigned short* wr = wqb + (size_t)(ot * 16 + l16) * CCH;
        f4 acc = {0.f, 0.f, 0.f, 0.f};
#pragma unroll
        for (int kk = 0; kk < 4; ++kk) {
            const bf8 a = *(const bf8*)&wr[kk * 32 + quad * 8];
            const unsigned short* xr = &xnb[l16 * 138 + kk * 32 + quad * 8];
            union { unsigned u[4]; bf8 v; } bx;
            bx.u[0] = *(const unsigned*)&xr[0];
            bx.u[1] = *(const unsigned*)&xr[2];
            bx.u[2] = *(const unsigned*)&xr[4];
            bx.u[3] = *(const unsigned*)&xr[6];
            acc = MFMA(a, bx.v, acc);
        }
        // C-frag: col(px)=l16, row o = ot*16 + quad*4 + r
        if (ot < 16) {
            const int h  = (ot >> 1) & 3;
            const int d0 = (ot & 1) * 16 + quad * 4;
            const int bh = b * 4 + h;
            unsigned short* dst = ((ot < 8) ? qh : kh)
                                + ((size_t)bh * NPIX + n0 + l16) * 32 + d0;
            uint2 wp;
            wp.x = pk2r(acc.x, acc.y);
            wp.y = pk2r(acc.z, acc.w);
            *(uint2*)dst = wp;
        } else {
            const int bh = b * 4 + ((ot - 16) >> 1);
            const int dv = ((ot - 16) & 1) * 16 + quad * 4;
#pragma unroll
            for (int r = 0; r < 4; ++r)
                vth[((size_t)bh * 32 + dv + r) * NPIX + n0 + l16] = f2bf(acc[r]);
        }
    }
}

// ---------------------------------------------------------------------------
// Kernel 2: MFMA flash attention. R9 (UNCHANGED): 256 thr, 4 waves,
// qA+qB per wave, per-block K/V staging via global_load_lds (double-
// buffered, XOR-swizzled), P transpose in-register via permlane swaps.
// ---------------------------------------------------------------------------
struct Frags { bf8 k0, k1, v0, v1; };

// in-register S^T -> PV-B-frag transpose: 2x permlane32_swap + 2x permlane16_swap
__device__ __forceinline__ void xpose(unsigned x0, unsigned y0,
                                      unsigned x1, unsigned y1,
                                      unsigned* u /*[4]*/)
{
    auto sx = __builtin_amdgcn_permlane32_swap(x0, x1, false, false);
    auto sy = __builtin_amdgcn_permlane32_swap(y0, y1, false, false);
    auto dx = __builtin_amdgcn_permlane16_swap(sx[0], sx[1], false, false);
    auto dy = __builtin_amdgcn_permlane16_swap(sy[0], sy[1], false, false);
    u[0] = dx[0]; u[1] = dy[0]; u[2] = dx[1]; u[3] = dy[1];
}

__device__ __forceinline__ void tileCompute(const Frags& f,
    const bf8 qA, const bf8 qB, const bf8 ones,
    f4& o00, f4& o10, f4& o01, f4& o11, f4& lA, f4& lB)
{
    const f4 z = {0.f, 0.f, 0.f, 0.f};
    f4 sA0 = MFMA(f.k0, qA, z);
    f4 sA1 = MFMA(f.k1, qA, z);
    f4 sB0 = MFMA(f.k0, qB, z);
    f4 sB1 = MFMA(f.k1, qB, z);

    // P = exp2(S), packed as key-pair dwords (truncating)
    const unsigned a0x = pk2t(__builtin_amdgcn_exp2f(sA0.x), __builtin_amdgcn_exp2f(sA0.y));
    const unsigned a0y = pk2t(__builtin_amdgcn_exp2f(sA0.z), __builtin_amdgcn_exp2f(sA0.w));
    const unsigned a1x = pk2t(__builtin_amdgcn_exp2f(sA1.x), __builtin_amdgcn_exp2f(sA1.y));
    const unsigned a1y = pk2t(__builtin_amdgcn_exp2f(sA1.z), __builtin_amdgcn_exp2f(sA1.w));
    const unsigned b0x = pk2t(__builtin_amdgcn_exp2f(sB0.x), __builtin_amdgcn_exp2f(sB0.y));
    const unsigned b0y = pk2t(__builtin_amdgcn_exp2f(sB0.z), __builtin_amdgcn_exp2f(sB0.w));
    const unsigned b1x = pk2t(__builtin_amdgcn_exp2f(sB1.x), __builtin_amdgcn_exp2f(sB1.y));
    const unsigned b1y = pk2t(__builtin_amdgcn_exp2f(sB1.z), __builtin_amdgcn_exp2f(sB1.w));

    union { unsigned u[4]; bf8 v; } pA, pB;
    xpose(a0x, a0y, a1x, a1y, pA.u);
    xpose(b0x, b0y, b1x, b1y, pB.u);

    o00 = MFMA(f.v0, pA.v, o00); o10 = MFMA(f.v1, pA.v, o10);
    o01 = MFMA(f.v0, pB.v, o01); o11 = MFMA(f.v1, pB.v, o11);
    lA  = MFMA(ones, pA.v, lA);  lB  = MFMA(ones, pB.v, lB);
}

__global__ __launch_bounds__(256, 4) void flash_kernel(
    const unsigned short* __restrict__ qh, const unsigned short* __restrict__ kh,
    const unsigned short* __restrict__ vth,
    float* __restrict__ ao, float* __restrict__ lbuf)
{
    const int blk = blockIdx.x;
    const int bh  = (blk & 7) + 8 * ((blk >> 3) & 1);   // XCD-local per bh
    const int rem = blk >> 4;
    const int qt  = rem & 31;
    const int ks  = rem >> 5;                            // 0..1
    const int t   = threadIdx.x;
    const int wv  = t >> 6;
    const int l16 = t & 15;
    const int quad = (t & 63) >> 4;
    const int q0  = qt * 128 + wv * 32;

    // double-buffered K/V tile: [buf][K 32x(32d) | V 32dx(32n)], bf16
    __shared__ __align__(16) unsigned short kv[2][2048];

    const size_t qbaseA = ((size_t)bh * NPIX + q0 + l16) * 32 + quad * 8;
    const bf8 qA = *(const bf8*)&qh[qbaseA];
    const bf8 qB = *(const bf8*)&qh[qbaseA + 16 * 32];

    const unsigned short* khb = kh  + (size_t)bh * NPIX * 32;
    const unsigned short* vhb = vth + (size_t)bh * 32 * NPIX;

    // staging geometry: wave wv stages chunk wv (1KB): lane -> 16B slot.
    // chunk rows are multiples of 16, so swizzled col = (lane&3)^((lane>>3)&3).
    const int lane = t & 63;
    const int srow = lane >> 2;
    const int scol = (lane & 3) ^ ((lane >> 3) & 3);
    lu32* ldsbase[2];
    ldsbase[0] = (lu32*)&kv[0][wv * 512];
    ldsbase[1] = (lu32*)&kv[1][wv * 512];

    const short one = (short)0x3f80;
    const bf8 ones = {one, one, one, one, one, one, one, one};

    const f4 z = {0.f, 0.f, 0.f, 0.f};
    f4 o00 = z, o10 = z, o01 = z, o11 = z, lA = z, lB = z;

    const int jbase = ks * 2048;

    // K chunks (wv 0,1): rows = keys, source row j0+wv*16+srow, 64B rows.
    // V chunks (wv 2,3): rows = d, source row (wv-2)*16+srow, stride NPIX.
#define STAGE(bufi, j0s)                                                        \
    {                                                                           \
        const unsigned short* gsrc = (wv < 2)                                   \
            ? khb + (size_t)((j0s) + wv * 16 + srow) * 32 + scol * 8            \
            : vhb + (size_t)((wv - 2) * 16 + srow) * NPIX + (j0s) + scol * 8;   \
        __builtin_amdgcn_global_load_lds((gu32*)gsrc, ldsbase[bufi], 16, 0, 0); \
    }

    STAGE(0, jbase);
    __syncthreads();

    const int sk = (quad ^ ((l16 >> 1) & 3)) * 8;   // swizzled 16B slot (shorts)
    for (int jt = 0; jt < 64; ++jt) {
        const int cur = jt & 1;
        if (jt < 63) STAGE(cur ^ 1, jbase + (jt + 1) * 32);
        const unsigned short* kb = kv[cur];
        Frags f;
        f.k0 = *(const bf8*)&kb[l16 * 32 + sk];
        f.k1 = *(const bf8*)&kb[(16 + l16) * 32 + sk];
        f.v0 = *(const bf8*)&kb[1024 + l16 * 32 + sk];
        f.v1 = *(const bf8*)&kb[1024 + (16 + l16) * 32 + sk];
        tileCompute(f, qA, qB, ones, o00, o10, o01, o11, lA, lB);
        __syncthreads();   // drains vmcnt (stage done) + lgkm (reads done)
    }
#undef STAGE

    // epilogue: fp32 stores, full 128B line coverage per wave (A+B adjacent)
    float* aos = ao + (size_t)ks * 2097152;
    float* lbs = lbuf + (size_t)ks * 65536;
    float* aoA = aos + (size_t)bh * 32 * NPIX + q0 + l16;
    float* aoB = aoA + 16;
#pragma unroll
    for (int r = 0; r < 4; ++r) {
        aoA[(size_t)(quad * 4 + r) * NPIX]      = o00[r];
        aoA[(size_t)(16 + quad * 4 + r) * NPIX] = o10[r];
        aoB[(size_t)(quad * 4 + r) * NPIX]      = o01[r];
        aoB[(size_t)(16 + quad * 4 + r) * NPIX] = o11[r];
    }
    if (quad == 0) {
        lbs[(size_t)bh * NPIX + q0 + l16]      = lA.x;
        lbs[(size_t)bh * NPIX + q0 + 16 + l16] = lB.x;
    }
}

// ---------------------------------------------------------------------------
// Kernel 3: R10 — parts MERGED, 16-pixel tiles, grid 1024. Preamble (ao
// sum+normalize+pack) runs once; each wave computes both 64-channel halves
// reusing the same B-frags. ao read traffic halves (32 MB -> 16 MB).
// ---------------------------------------------------------------------------
__global__ __launch_bounds__(256) void proj_kernel(
    const float* __restrict__ ao, const float* __restrict__ lbuf,
    const unsigned short* __restrict__ wob, const float* __restrict__ b_out,
    float* __restrict__ out)
{
    const int blk  = blockIdx.x;
    const int b  = blk >> 8;
    const int n0 = (blk & 255) << 4;
    const int t  = threadIdx.x;
    const int wv = t >> 6;
    const int l16 = t & 15;
    const int quad = (t & 63) >> 4;

    __shared__ unsigned short xsb[16 * 138];   // [pix][c], stride 138
    __shared__ float linv[4][16];

    if (t < 64) {
        int h = t >> 4, p = t & 15;
        size_t li = (size_t)(b * 4 + h) * NPIX + n0 + p;
        linv[h][p] = 1.0f / (lbuf[li] + lbuf[li + 65536]);
    }
    __syncthreads();

    const float* a0 = ao + (size_t)(b * CCH) * NPIX + n0;
    const float* a1 = a0 + 2097152;
#pragma unroll
    for (int k = 0; k < 2; ++k) {
        int idx = k * 256 + t;                 // 512 float4 slots
        int c = idx >> 2, p4 = (idx & 3) * 4;
        const float4 va = *(const float4*)&a0[(size_t)c * NPIX + p4];
        const float4 vb = *(const float4*)&a1[(size_t)c * NPIX + p4];
        const int hh = c >> 5;
        xsb[(p4 + 0) * 138 + c] = f2bf((va.x + vb.x) * linv[hh][p4 + 0]);
        xsb[(p4 + 1) * 138 + c] = f2bf((va.y + vb.y) * linv[hh][p4 + 1]);
        xsb[(p4 + 2) * 138 + c] = f2bf((va.z + vb.z) * linv[hh][p4 + 2]);
        xsb[(p4 + 3) * 138 + c] = f2bf((va.w + vb.w) * linv[hh][p4 + 3]);
    }
    __syncthreads();

    // B-frags once, reused for both output halves
    bf8 pbf[4];
#pragma unroll
    for (int kk = 0; kk < 4; ++kk) {
        const unsigned short* row = &xsb[l16 * 138 + kk * 32 + quad * 8];
        union { unsigned u[4]; bf8 v; } pb;
        pb.u[0] = *(const unsigned*)&row[0];
        pb.u[1] = *(const unsigned*)&row[2];
        pb.u[2] = *(const unsigned*)&row[4];
        pb.u[3] = *(const unsigned*)&row[6];
        pbf[kk] = pb.v;
    }

    const f4 z = {0.f, 0.f, 0.f, 0.f};
#pragma unroll
    for (int p = 0; p < 2; ++p) {
        const int o0 = p * 64 + wv * 16;
        const unsigned short* wrow = wob + (size_t)(o0 + l16) * CCH;
        f4 acc = z;
#pragma unroll
        for (int kk = 0; kk < 4; ++kk) {
            const bf8 aw = *(const bf8*)&wrow[kk * 32 + quad * 8];
            acc = MFMA(aw, pbf[kk], acc);
        }
#pragma unroll
        for (int r = 0; r < 4; ++r) {
            const int o = o0 + quad * 4 + r;
            out[(size_t)(b * CCH + o) * NPIX + n0 + l16] = acc[r] + b_out[o];
        }
    }
}

// ---------------------------------------------------------------------------
extern "C" void kernel_launch(void* const* d_in, const int* in_sizes, int n_in,
                              void* d_out, int out_size, void* d_ws, size_t ws_size,
                              hipStream_t stream) {
    const float* x     = (const float*)d_in[0];
    const float* g     = (const float*)d_in[1];
    const float* bvec  = (const float*)d_in[2];
    const float* w_qkv = (const float*)d_in[3];
    const float* w_out = (const float*)d_in[4];
    const float* b_out = (const float*)d_in[5];
    float* out = (float*)d_out;

    char* ws = (char*)d_ws;
    float*          lbuf = (float*)(ws);                      // 0..512K
    unsigned short* wqb  = (unsigned short*)(ws + (1u << 20));
    unsigned short* wob  = (unsigned short*)(ws + (3u << 19)); // 1.5M
    unsigned short* qh   = (unsigned short*)(ws + (4u  << 20));
    unsigned short* kh   = (unsigned short*)(ws + (8u  << 20));
    unsigned short* vth  = (unsigned short*)(ws + (12u << 20));
    float*          ao   = (float*)(ws + (16u << 20));        // 2 slices x 8MB

    wconv_kernel<<<dim3(256),  dim3(256), 0, stream>>>(w_qkv, w_out, wqb, wob);
    lnqkv_kernel<<<dim3(1024), dim3(256), 0, stream>>>(x, g, bvec, wqb, qh, kh, vth);
    flash_kernel<<<dim3(1024), dim3(256), 0, stream>>>(qh, kh, vth, ao, lbuf);
    proj_kernel <<<dim3(1024), dim3(256), 0, stream>>>(ao, lbuf, wob, b_out, out);
}